// Round 1
// 210.303 us; speedup vs baseline: 1.0890x; 1.0890x over previous
//
#include <hip/hip_runtime.h>

// Flash attention, non-causal: O = softmax(Q K^T / sqrt(64)) V
// B=64, S=2048, D=64, fp32 in/out, bf16 MFMA compute (fp32 accum).
//
// R11 = R10 (145us) + VALU-issue diet. Counters showed issue-slot
// saturation (VALU 40% + MFMA 22.5% + LDS ~12%), so:
//  (a) 512-thread / 8-wave blocks, q-tile 256: K/V staging (loads+packs)
//      amortizes over 2x the q-rows -> per-wave staging halves. Occupancy
//      unchanged: 2 blocks/CU x 8 waves = 16 waves/CU, LDS 54KB*2=108KB.
//  (b) pk2 = v_cvt_pk_bf16_f32 (1 instr, RNE) instead of 3-op round-half-up.
//  (c) persistent zero f32x4 as C operand of the first QK mfma (D!=C),
//      removing 32 v_mov zero-inits per iteration.

typedef short bf16x8 __attribute__((ext_vector_type(8)));
typedef float f32x4 __attribute__((ext_vector_type(4)));

#define SQK 0.18033688011112042f /* (1/8) * log2(e) : softmax in exp2 domain */

__device__ __forceinline__ short f2bf(float x) {
  unsigned u = __float_as_uint(x);
  u = (u + 0x7fffu + ((u >> 16) & 1u)) >> 16;  // RNE (one-time Q conv only)
  return (short)u;
}

// pack two floats to bf16x2 in ONE instruction (RNE): lo -> [15:0], hi -> [31:16]
__device__ __forceinline__ unsigned pk2(float lo, float hi) {
  unsigned r;
  asm("v_cvt_pk_bf16_f32 %0, %1, %2" : "=v"(r) : "v"(lo), "v"(hi));
  return r;
}

__global__ __launch_bounds__(512) void DotProductAttention_44573170598739_kernel(
    const float* __restrict__ Q, const float* __restrict__ K,
    const float* __restrict__ V, float* __restrict__ O) {
  constexpr int S = 2048, D = 64;
  const int b   = blockIdx.x;                // batch (XCD-locality swizzle)
  const int q0  = blockIdx.y * 256;          // block's first q row
  const int tid = threadIdx.x;
  const int w    = tid >> 6;                 // wave 0..7
  const int lane = tid & 63;
  const int qh   = lane >> 4;                // quad 0..3
  const int r    = lane & 15;

  __shared__ __align__(16) short ksh[64 * 72];      // K tile, row-major [key][d]
  __shared__ __align__(16) short vsh[64 * 72];      // V tile, transposed [d][key]
  __shared__ __align__(16) short psh[8][32 * 72];   // per-wave P, BOTH strips

  // ---- Q fragments (regs, whole kernel), pre-scaled into exp2 domain.
  bf16x8 qf[2][2];
#pragma unroll
  for (int s = 0; s < 2; ++s)
#pragma unroll
    for (int c = 0; c < 2; ++c) {
      const float* qp = Q + ((size_t)b * S + q0 + w * 32 + s * 16 + r) * D + c * 32 + qh * 8;
      float4 x = ((const float4*)qp)[0];
      float4 y = ((const float4*)qp)[1];
      bf16x8 f;
      f[0] = f2bf(x.x * SQK); f[1] = f2bf(x.y * SQK);
      f[2] = f2bf(x.z * SQK); f[3] = f2bf(x.w * SQK);
      f[4] = f2bf(y.x * SQK); f[5] = f2bf(y.y * SQK);
      f[6] = f2bf(y.z * SQK); f[7] = f2bf(y.w * SQK);
      qf[s][c] = f;
    }

  // all-ones B fragment for row-sum mfma
  bf16x8 onesf;
#pragma unroll
  for (int i = 0; i < 8; ++i) onesf[i] = (short)0x3F80;

  f32x4 oacc[2][4] = {};      // [strip][d-tile], C-layout (row=q, col=d)
  f32x4 sacc[2] = {};         // row sums: sacc[s][g] = sum for q = 4qh+g
  const f32x4 zf = {};        // persistent zero C-operand (never written)

  const float* Kb = K + (size_t)b * S * D;
  const float* Vb = V + (size_t)b * S * D;

  // ---- prologue: K and V tile 0 into prefetch regs
  float4 kx[2];
  float  vv[8];
#pragma unroll
  for (int i = 0; i < 2; ++i)
    kx[i] = ((const float4*)Kb)[tid + 512 * i];
#pragma unroll
  for (int j = 0; j < 8; ++j)
    vv[j] = Vb[(w * 8 + j) * D + lane];

  for (int kt = 0; kt < S; kt += 64) {
    // ---- phase A: pack+write K and V tiles from prefetch regs (no waits)
#pragma unroll
    for (int i = 0; i < 2; ++i) {
      int f = 4 * tid + 2048 * i;
      int row = f >> 6, col = f & 63;
      uint2 pk = { pk2(kx[i].x, kx[i].y), pk2(kx[i].z, kx[i].w) };
      *(uint2*)&ksh[row * 72 + col] = pk;
    }
#pragma unroll
    for (int jj = 0; jj < 2; ++jj) {
      uint2 pk = { pk2(vv[4 * jj + 0], vv[4 * jj + 1]),
                   pk2(vv[4 * jj + 2], vv[4 * jj + 3]) };
      *(uint2*)&vsh[lane * 72 + w * 8 + 4 * jj] = pk;
    }
    __syncthreads();

    // ---- phase B: fragment reads, then immediately issue next K/V loads
    bf16x8 kf[4][2], vf[4][2];
#pragma unroll
    for (int t = 0; t < 4; ++t)
#pragma unroll
      for (int c = 0; c < 2; ++c) {
        kf[t][c] = *(const bf16x8*)&ksh[(t * 16 + r) * 72 + c * 32 + qh * 8];
        vf[t][c] = *(const bf16x8*)&vsh[(t * 16 + r) * 72 + c * 32 + qh * 8];
      }

    // prefetch K/V tile kt+64 (clamped; last-iter values unused). Latency
    // rides across the whole compute phase; the compiler's vmcnt before
    // next phase A's consumption guarantees arrival.
    {
      const int kt2 = (kt + 64 < S) ? kt + 64 : 0;
      const float* Kg2 = Kb + (size_t)kt2 * D;
      const float* Vg2 = Vb + (size_t)kt2 * D;
#pragma unroll
      for (int i = 0; i < 2; ++i)
        kx[i] = ((const float4*)Kg2)[tid + 512 * i];
#pragma unroll
      for (int j = 0; j < 8; ++j)
        vv[j] = Vg2[(w * 8 + j) * D + lane];
    }

    // ---- both strips: S^T = K Q^T, exp2, P-write. No drain in between.
#pragma unroll
    for (int s = 0; s < 2; ++s) {
      f32x4 sc[4];
#pragma unroll
      for (int t = 0; t < 4; ++t) {
        f32x4 z = __builtin_amdgcn_mfma_f32_16x16x32_bf16(kf[t][0], qf[s][0], zf, 0, 0, 0);
        z = __builtin_amdgcn_mfma_f32_16x16x32_bf16(kf[t][1], qf[s][1], z, 0, 0, 0);
        sc[t] = z;
      }
#pragma unroll
      for (int t = 0; t < 4; ++t)
#pragma unroll
        for (int g = 0; g < 4; ++g)
          sc[t][g] = __builtin_amdgcn_exp2f(sc[t][g]);
#pragma unroll
      for (int t = 0; t < 4; ++t) {
        uint2 pk = { pk2(sc[t][0], sc[t][1]), pk2(sc[t][2], sc[t][3]) };
        *(uint2*)&psh[w][(s * 16 + r) * 72 + t * 16 + 4 * qh] = pk;
      }
    }

    // ---- single drain, then PV (+ row-sum mfma) for both strips
    __asm__ volatile("s_waitcnt lgkmcnt(0)" ::: "memory");
#pragma unroll
    for (int s = 0; s < 2; ++s)
#pragma unroll
      for (int c = 0; c < 2; ++c) {
        bf16x8 pf = *(const bf16x8*)&psh[w][(s * 16 + r) * 72 + c * 32 + qh * 8];
        sacc[s] = __builtin_amdgcn_mfma_f32_16x16x32_bf16(pf, onesf, sacc[s], 0, 0, 0);
#pragma unroll
        for (int dt = 0; dt < 4; ++dt)
          oacc[s][dt] = __builtin_amdgcn_mfma_f32_16x16x32_bf16(pf, vf[dt][c], oacc[s][dt], 0, 0, 0);
      }
    __syncthreads();
  }

  // ---- epilogue: sacc[s][g] is the row sum for q = 4qh+g (every lane)
#pragma unroll
  for (int s = 0; s < 2; ++s)
#pragma unroll
    for (int g = 0; g < 4; ++g) {
      float inv = 1.0f / sacc[s][g];
      int q = q0 + w * 32 + s * 16 + 4 * qh + g;
      float* op = O + ((size_t)b * S + q) * D + r;
#pragma unroll
      for (int dt = 0; dt < 4; ++dt)
        op[dt * 16] = oacc[s][dt][g] * inv;
    }
}

extern "C" void kernel_launch(void* const* d_in, const int* in_sizes, int n_in,
                              void* d_out, int out_size, void* d_ws, size_t ws_size,
                              hipStream_t stream) {
  (void)in_sizes; (void)n_in; (void)out_size; (void)d_ws; (void)ws_size;
  const float* Q = (const float*)d_in[0];
  const float* K = (const float*)d_in[1];
  const float* V = (const float*)d_in[2];
  float* O = (float*)d_out;
  // grid.x = batch so all q-tile blocks of a batch share an XCD (L2 reuse)
  dim3 grid(64, 2048 / 256, 1);
  dim3 block(512, 1, 1);
  hipLaunchKernelGGL(DotProductAttention_44573170598739_kernel,
                     grid, block, 0, stream, Q, K, V, O);
}

// Round 3
// 202.425 us; speedup vs baseline: 1.1314x; 1.0389x over previous
//
#include <hip/hip_runtime.h>

// Flash attention, non-causal: O = softmax(Q K^T / sqrt(64)) V
// B=64, S=2048, D=64, fp32 in/out, bf16 MFMA compute (fp32 accum).
//
// R13 = R12 (failed) with the permlane transpose ELIMINATED. R12's error
// was consistent with a flipped v_permlane32_swap direction (raw asm,
// unverified semantics). Fix: keep P in its natural C/D output order
// (key = (j&3)+8*(j>>2)+4*hi, the HW-verified m74/m101 mapping) and
// permute V's LDS columns at staging instead (swap key groups 4-7 <-> 8-11
// within each 16-key block). PV's A and B then agree element-for-element
// with ONE b128 V read and zero cross-lane ops. Also: row sums via
// per-lane f32 adds on the live e-values (q=r32 is lane-local) instead of
// a row-sum MFMA -- frees 16 VGPR + 4 MFMA/iter; t-loop split to halve
// sc/kf liveness. MFMA/iter 36 -> 16 vs R11; psh and its drain deleted.

typedef short bf16x8 __attribute__((ext_vector_type(8)));
typedef float f32x16 __attribute__((ext_vector_type(16)));

#define SQK 0.18033688011112042f /* (1/8) * log2(e) : softmax in exp2 domain */

__device__ __forceinline__ short f2bf(float x) {
  unsigned u = __float_as_uint(x);
  u = (u + 0x7fffu + ((u >> 16) & 1u)) >> 16;  // RNE (one-time Q conv only)
  return (short)u;
}

// pack two floats to bf16x2 in ONE instruction (RNE): lo -> [15:0], hi -> [31:16]
__device__ __forceinline__ unsigned pk2(float lo, float hi) {
  unsigned r;
  asm("v_cvt_pk_bf16_f32 %0, %1, %2" : "=v"(r) : "v"(lo), "v"(hi));
  return r;
}

__global__ __launch_bounds__(512) void DotProductAttention_44573170598739_kernel(
    const float* __restrict__ Q, const float* __restrict__ K,
    const float* __restrict__ V, float* __restrict__ O) {
  constexpr int S = 2048, D = 64;
  const int b   = blockIdx.x;                // batch (XCD-locality swizzle)
  const int q0  = blockIdx.y * 256;          // block's first q row
  const int tid = threadIdx.x;
  const int w    = tid >> 6;                 // wave 0..7, owns 32 q rows
  const int lane = tid & 63;
  const int hi   = lane >> 5;                // half-wave 0/1
  const int r32  = lane & 31;

  __shared__ __align__(16) short ksh[64 * 72];  // K tile, row-major [key][d]
  __shared__ __align__(16) short vsh[64 * 72];  // V tile, [d][col], cols permuted:
                                                // within each 16-key block,
                                                // col = (k&3) | ((k&4)<<1) | ((k&8)>>1)

  // ---- Q fragments (regs, whole kernel), pre-scaled into exp2 domain.
  // B-operand of swapped QK: qf[dd] = Q[q = q0+w*32+r32][d = 16dd + 8hi + j]
  bf16x8 qf[4];
#pragma unroll
  for (int dd = 0; dd < 4; ++dd) {
    const float* qp = Q + ((size_t)b * S + q0 + w * 32 + r32) * D + dd * 16 + hi * 8;
    float4 x = ((const float4*)qp)[0];
    float4 y = ((const float4*)qp)[1];
    bf16x8 f;
    f[0] = f2bf(x.x * SQK); f[1] = f2bf(x.y * SQK);
    f[2] = f2bf(x.z * SQK); f[3] = f2bf(x.w * SQK);
    f[4] = f2bf(y.x * SQK); f[5] = f2bf(y.y * SQK);
    f[6] = f2bf(y.z * SQK); f[7] = f2bf(y.w * SQK);
    qf[dd] = f;
  }

  f32x16 oacc[2] = {};        // O: D[row=q(16 rows)][col = d = 32dt + r32]
  float rs = 0.f;             // this lane's share of rowsum[q = r32]
  const f32x16 z16 = {};      // persistent zero C-operand (never written)

  const float* Kb = K + (size_t)b * S * D;
  const float* Vb = V + (size_t)b * S * D;

  // ---- prologue: K and V tile 0 into prefetch regs
  float4 kx[2];
  float  vv[8];
#pragma unroll
  for (int i = 0; i < 2; ++i)
    kx[i] = ((const float4*)Kb)[tid + 512 * i];
#pragma unroll
  for (int j = 0; j < 8; ++j)
    vv[j] = Vb[(w * 8 + j) * D + lane];

  // V staging column base: wave w holds keys w*8+0..7 = 16-block (w>>1),
  // sub-half (w&1). Permuted cols: j<4 -> 4*(w&1)+j ; j>=4 -> 8+4*(w&1)+(j-4).
  const int vcb = 16 * (w >> 1) + 4 * (w & 1);

  for (int kt = 0; kt < S; kt += 64) {
    // ---- phase A: pack+write K and V tiles from prefetch regs (no waits)
#pragma unroll
    for (int i = 0; i < 2; ++i) {
      int f = 4 * tid + 2048 * i;
      int row = f >> 6, col = f & 63;
      uint2 pk = { pk2(kx[i].x, kx[i].y), pk2(kx[i].z, kx[i].w) };
      *(uint2*)&ksh[row * 72 + col] = pk;
    }
    {
      uint2 plo = { pk2(vv[0], vv[1]), pk2(vv[2], vv[3]) };
      uint2 phi = { pk2(vv[4], vv[5]), pk2(vv[6], vv[7]) };
      *(uint2*)&vsh[lane * 72 + vcb]     = plo;
      *(uint2*)&vsh[lane * 72 + vcb + 8] = phi;
    }
    __syncthreads();

#pragma unroll
    for (int t = 0; t < 2; ++t) {
      // K fragments (A-operand): kf[dd] = K[key=32t+r32][d=16dd+8hi+j]
      bf16x8 kf[4];
#pragma unroll
      for (int dd = 0; dd < 4; ++dd)
        kf[dd] = *(const bf16x8*)&ksh[(t * 32 + r32) * 72 + dd * 16 + hi * 8];

      if (t == 0) {
        // prefetch K/V tile kt+64 (clamped; last-iter values unused).
        const int kt2 = (kt + 64 < S) ? kt + 64 : 0;
        const float* Kg2 = Kb + (size_t)kt2 * D;
        const float* Vg2 = Vb + (size_t)kt2 * D;
#pragma unroll
        for (int i = 0; i < 2; ++i)
          kx[i] = ((const float4*)Kg2)[tid + 512 * i];
#pragma unroll
        for (int j = 0; j < 8; ++j)
          vv[j] = Vg2[(w * 8 + j) * D + lane];
      }

      // ---- QK^T swapped: z = K_tile(32 keys) x Q^T(32 q), accum over d.
      // D[row = key_in_tile = (reg&3)+8(reg>>2)+4hi][col = q = r32]
      f32x16 z = __builtin_amdgcn_mfma_f32_32x32x16_bf16(kf[0], qf[0], z16, 0, 0, 0);
      z = __builtin_amdgcn_mfma_f32_32x32x16_bf16(kf[1], qf[1], z, 0, 0, 0);
      z = __builtin_amdgcn_mfma_f32_32x32x16_bf16(kf[2], qf[2], z, 0, 0, 0);
      z = __builtin_amdgcn_mfma_f32_32x32x16_bf16(kf[3], qf[3], z, 0, 0, 0);

      // ---- per 16-key half: exp2, row-sum add, pack, PV mfma.
      // e[i] = P[q=r32][key = base + (i&3)+8(i>>2)+4hi], base = 32t+16h.
      // pa element j = e[j]; vsh's permuted cols make vf element j the
      // matching V row, so placement agrees without any lane exchange.
#pragma unroll
      for (int h = 0; h < 2; ++h) {
        float e0 = __builtin_amdgcn_exp2f(z[8 * h + 0]);
        float e1 = __builtin_amdgcn_exp2f(z[8 * h + 1]);
        float e2 = __builtin_amdgcn_exp2f(z[8 * h + 2]);
        float e3 = __builtin_amdgcn_exp2f(z[8 * h + 3]);
        float e4 = __builtin_amdgcn_exp2f(z[8 * h + 4]);
        float e5 = __builtin_amdgcn_exp2f(z[8 * h + 5]);
        float e6 = __builtin_amdgcn_exp2f(z[8 * h + 6]);
        float e7 = __builtin_amdgcn_exp2f(z[8 * h + 7]);
        rs += ((e0 + e1) + (e2 + e3)) + ((e4 + e5) + (e6 + e7));
        union { bf16x8 v; unsigned u[4]; } pu;
        pu.u[0] = pk2(e0, e1); pu.u[1] = pk2(e2, e3);
        pu.u[2] = pk2(e4, e5); pu.u[3] = pk2(e6, e7);

        const int cb = t * 32 + h * 16 + hi * 8;
        bf16x8 vf0 = *(const bf16x8*)&vsh[(r32) * 72 + cb];
        bf16x8 vf1 = *(const bf16x8*)&vsh[(32 + r32) * 72 + cb];

        oacc[0] = __builtin_amdgcn_mfma_f32_32x32x16_bf16(pu.v, vf0, oacc[0], 0, 0, 0);
        oacc[1] = __builtin_amdgcn_mfma_f32_32x32x16_bf16(pu.v, vf1, oacc[1], 0, 0, 0);
      }
    }
    __syncthreads();
  }

  // ---- epilogue: full rowsum for q=r32 (combine both hi halves), then
  // gather the rowsum each oacc row needs via one-time shfls.
  float tot = rs + __shfl_xor(rs, 32);
#pragma unroll
  for (int g = 0; g < 16; ++g) {
    int rq = (g & 3) + 8 * (g >> 2) + 4 * hi;   // q-offset within wave's 32
    float inv = 1.0f / __shfl(tot, rq);          // lane rq holds rowsum[q=rq]
    int q = q0 + w * 32 + rq;
    float* op = O + ((size_t)b * S + q) * D + r32;
    op[0]  = oacc[0][g] * inv;
    op[32] = oacc[1][g] * inv;
  }
}

extern "C" void kernel_launch(void* const* d_in, const int* in_sizes, int n_in,
                              void* d_out, int out_size, void* d_ws, size_t ws_size,
                              hipStream_t stream) {
  (void)in_sizes; (void)n_in; (void)out_size; (void)d_ws; (void)ws_size;
  const float* Q = (const float*)d_in[0];
  const float* K = (const float*)d_in[1];
  const float* V = (const float*)d_in[2];
  float* O = (float*)d_out;
  // grid.x = batch so all q-tile blocks of a batch share an XCD (L2 reuse)
  dim3 grid(64, 2048 / 256, 1);
  dim3 block(512, 1, 1);
  hipLaunchKernelGGL(DotProductAttention_44573170598739_kernel,
                     grid, block, 0, stream, Q, K, V, O);
}

// Round 4
// 190.707 us; speedup vs baseline: 1.2009x; 1.0614x over previous
//
#include <hip/hip_runtime.h>

// Flash attention, non-causal: O = softmax(Q K^T / sqrt(64)) V
// B=64, S=2048, D=64, fp32 in/out, bf16 MFMA compute (fp32 accum).
//
// R14 = R13 (115.7us) + LDS double-buffer, ONE barrier per k-iter, and
// s_setprio around the MFMA clusters.
// R13 post-mortem: MFMA 24% + VALU 30% + LDS-pipe ~40% summed to ~94% of
// wall time -- pipes SERIALIZE because two block-wide barriers per iter
// keep all 8 waves in lockstep phase (all ds_read together, all MFMA
// together). Double-buffering kills the write->barrier->read chain: iter
// kt stages tile kt+64 into buf[p^1] (regs loaded last iter), issues
// loads for kt+128, computes from buf[p], one barrier. Waves drift ->
// pipes overlap across waves; setprio (T5) exploits exactly that
// diversity. Layouts/math identical to R13 (verified).

typedef short bf16x8 __attribute__((ext_vector_type(8)));
typedef float f32x16 __attribute__((ext_vector_type(16)));

#define SQK 0.18033688011112042f /* (1/8) * log2(e) : softmax in exp2 domain */

__device__ __forceinline__ short f2bf(float x) {
  unsigned u = __float_as_uint(x);
  u = (u + 0x7fffu + ((u >> 16) & 1u)) >> 16;  // RNE (one-time Q conv only)
  return (short)u;
}

// pack two floats to bf16x2 in ONE instruction (RNE): lo -> [15:0], hi -> [31:16]
__device__ __forceinline__ unsigned pk2(float lo, float hi) {
  unsigned r;
  asm("v_cvt_pk_bf16_f32 %0, %1, %2" : "=v"(r) : "v"(lo), "v"(hi));
  return r;
}

__global__ __launch_bounds__(512, 4) void DotProductAttention_44573170598739_kernel(
    const float* __restrict__ Q, const float* __restrict__ K,
    const float* __restrict__ V, float* __restrict__ O) {
  constexpr int S = 2048, D = 64;
  const int b   = blockIdx.x;                // batch (XCD-locality swizzle)
  const int q0  = blockIdx.y * 256;          // block's first q row
  const int tid = threadIdx.x;
  const int w    = tid >> 6;                 // wave 0..7, owns 32 q rows
  const int lane = tid & 63;
  const int hi   = lane >> 5;                // half-wave 0/1
  const int r32  = lane & 31;

  // double-buffered tiles
  __shared__ __align__(16) short ksh[2][64 * 72];  // K tile, row-major [key][d]
  __shared__ __align__(16) short vsh[2][64 * 72];  // V tile, [d][col], cols permuted:
                                                   // within each 16-key block,
                                                   // col = (k&3) | ((k&4)<<1) | ((k&8)>>1)

  // ---- Q fragments (regs, whole kernel), pre-scaled into exp2 domain.
  // B-operand of swapped QK: qf[dd] = Q[q = q0+w*32+r32][d = 16dd + 8hi + j]
  bf16x8 qf[4];
#pragma unroll
  for (int dd = 0; dd < 4; ++dd) {
    const float* qp = Q + ((size_t)b * S + q0 + w * 32 + r32) * D + dd * 16 + hi * 8;
    float4 x = ((const float4*)qp)[0];
    float4 y = ((const float4*)qp)[1];
    bf16x8 f;
    f[0] = f2bf(x.x * SQK); f[1] = f2bf(x.y * SQK);
    f[2] = f2bf(x.z * SQK); f[3] = f2bf(x.w * SQK);
    f[4] = f2bf(y.x * SQK); f[5] = f2bf(y.y * SQK);
    f[6] = f2bf(y.z * SQK); f[7] = f2bf(y.w * SQK);
    qf[dd] = f;
  }

  f32x16 oacc[2] = {};        // O: D[row=q(16 rows)][col = d = 32dt + r32]
  float rs = 0.f;             // this lane's share of rowsum[q = r32]
  const f32x16 z16 = {};      // persistent zero C-operand (never written)

  const float* Kb = K + (size_t)b * S * D;
  const float* Vb = V + (size_t)b * S * D;

  // V staging column base: wave w holds keys w*8+0..7 = 16-block (w>>1),
  // sub-half (w&1). Permuted cols: j<4 -> 4*(w&1)+j ; j>=4 -> 8+4*(w&1)+(j-4).
  const int vcb = 16 * (w >> 1) + 4 * (w & 1);

  float4 kx[2];
  float  vv[8];

  // ---- prologue: tile 0 -> buf0; tile 1 loads left in flight
#pragma unroll
  for (int i = 0; i < 2; ++i)
    kx[i] = ((const float4*)Kb)[tid + 512 * i];
#pragma unroll
  for (int j = 0; j < 8; ++j)
    vv[j] = Vb[(w * 8 + j) * D + lane];
#pragma unroll
  for (int i = 0; i < 2; ++i) {
    int f = 4 * tid + 2048 * i;
    int row = f >> 6, col = f & 63;
    uint2 pk = { pk2(kx[i].x, kx[i].y), pk2(kx[i].z, kx[i].w) };
    *(uint2*)&ksh[0][row * 72 + col] = pk;
  }
  {
    uint2 plo = { pk2(vv[0], vv[1]), pk2(vv[2], vv[3]) };
    uint2 phi = { pk2(vv[4], vv[5]), pk2(vv[6], vv[7]) };
    *(uint2*)&vsh[0][lane * 72 + vcb]     = plo;
    *(uint2*)&vsh[0][lane * 72 + vcb + 8] = phi;
  }
#pragma unroll
  for (int i = 0; i < 2; ++i)
    kx[i] = ((const float4*)(Kb + 64 * D))[tid + 512 * i];
#pragma unroll
  for (int j = 0; j < 8; ++j)
    vv[j] = Vb[(64 + w * 8 + j) * D + lane];
  __syncthreads();

  int p = 0;
  for (int kt = 0; kt < S; kt += 64, p ^= 1) {
    // ---- stage tile kt+64 (regs from last iter) into buf p^1, then issue
    // loads for tile kt+128. Reads of buf[p^1] finished before the barrier
    // that ended iter kt-1, so these writes are race-free.
    if (kt + 64 < S) {
#pragma unroll
      for (int i = 0; i < 2; ++i) {
        int f = 4 * tid + 2048 * i;
        int row = f >> 6, col = f & 63;
        uint2 pk = { pk2(kx[i].x, kx[i].y), pk2(kx[i].z, kx[i].w) };
        *(uint2*)&ksh[p ^ 1][row * 72 + col] = pk;
      }
      {
        uint2 plo = { pk2(vv[0], vv[1]), pk2(vv[2], vv[3]) };
        uint2 phi = { pk2(vv[4], vv[5]), pk2(vv[6], vv[7]) };
        *(uint2*)&vsh[p ^ 1][lane * 72 + vcb]     = plo;
        *(uint2*)&vsh[p ^ 1][lane * 72 + vcb + 8] = phi;
      }
      if (kt + 128 < S) {
        const float* Kg2 = Kb + (size_t)(kt + 128) * D;
        const float* Vg2 = Vb + (size_t)(kt + 128) * D;
#pragma unroll
        for (int i = 0; i < 2; ++i)
          kx[i] = ((const float4*)Kg2)[tid + 512 * i];
#pragma unroll
        for (int j = 0; j < 8; ++j)
          vv[j] = Vg2[(w * 8 + j) * D + lane];
      }
    }

    const short* kshp = ksh[p];
    const short* vshp = vsh[p];
#pragma unroll
    for (int t = 0; t < 2; ++t) {
      // K fragments (A-operand): kf[dd] = K[key=32t+r32][d=16dd+8hi+j]
      bf16x8 kf[4];
#pragma unroll
      for (int dd = 0; dd < 4; ++dd)
        kf[dd] = *(const bf16x8*)&kshp[(t * 32 + r32) * 72 + dd * 16 + hi * 8];

      // ---- QK^T swapped: z = K_tile(32 keys) x Q^T(32 q), accum over d.
      // D[row = key_in_tile = (reg&3)+8(reg>>2)+4hi][col = q = r32]
      __builtin_amdgcn_s_setprio(1);
      f32x16 z = __builtin_amdgcn_mfma_f32_32x32x16_bf16(kf[0], qf[0], z16, 0, 0, 0);
      z = __builtin_amdgcn_mfma_f32_32x32x16_bf16(kf[1], qf[1], z, 0, 0, 0);
      z = __builtin_amdgcn_mfma_f32_32x32x16_bf16(kf[2], qf[2], z, 0, 0, 0);
      z = __builtin_amdgcn_mfma_f32_32x32x16_bf16(kf[3], qf[3], z, 0, 0, 0);
      __builtin_amdgcn_s_setprio(0);

      // ---- per 16-key half: exp2, row-sum add, pack, PV mfma.
      // e[i] = P[q=r32][key = base + (i&3)+8(i>>2)+4hi], base = 32t+16h.
      // vsh's permuted cols make vf element j the matching V row.
#pragma unroll
      for (int h = 0; h < 2; ++h) {
        float e0 = __builtin_amdgcn_exp2f(z[8 * h + 0]);
        float e1 = __builtin_amdgcn_exp2f(z[8 * h + 1]);
        float e2 = __builtin_amdgcn_exp2f(z[8 * h + 2]);
        float e3 = __builtin_amdgcn_exp2f(z[8 * h + 3]);
        float e4 = __builtin_amdgcn_exp2f(z[8 * h + 4]);
        float e5 = __builtin_amdgcn_exp2f(z[8 * h + 5]);
        float e6 = __builtin_amdgcn_exp2f(z[8 * h + 6]);
        float e7 = __builtin_amdgcn_exp2f(z[8 * h + 7]);
        rs += ((e0 + e1) + (e2 + e3)) + ((e4 + e5) + (e6 + e7));
        union { bf16x8 v; unsigned u[4]; } pu;
        pu.u[0] = pk2(e0, e1); pu.u[1] = pk2(e2, e3);
        pu.u[2] = pk2(e4, e5); pu.u[3] = pk2(e6, e7);

        const int cb = t * 32 + h * 16 + hi * 8;
        bf16x8 vf0 = *(const bf16x8*)&vshp[r32 * 72 + cb];
        bf16x8 vf1 = *(const bf16x8*)&vshp[(32 + r32) * 72 + cb];

        __builtin_amdgcn_s_setprio(1);
        oacc[0] = __builtin_amdgcn_mfma_f32_32x32x16_bf16(pu.v, vf0, oacc[0], 0, 0, 0);
        oacc[1] = __builtin_amdgcn_mfma_f32_32x32x16_bf16(pu.v, vf1, oacc[1], 0, 0, 0);
        __builtin_amdgcn_s_setprio(0);
      }
    }
    __syncthreads();
  }

  // ---- epilogue: full rowsum for q=r32 (combine both hi halves), then
  // gather the rowsum each oacc row needs via one-time shfls.
  float tot = rs + __shfl_xor(rs, 32);
#pragma unroll
  for (int g = 0; g < 16; ++g) {
    int rq = (g & 3) + 8 * (g >> 2) + 4 * hi;   // q-offset within wave's 32
    float inv = 1.0f / __shfl(tot, rq);          // lane rq holds rowsum[q=rq]
    int q = q0 + w * 32 + rq;
    float* op = O + ((size_t)b * S + q) * D + r32;
    op[0]  = oacc[0][g] * inv;
    op[32] = oacc[1][g] * inv;
  }
}

extern "C" void kernel_launch(void* const* d_in, const int* in_sizes, int n_in,
                              void* d_out, int out_size, void* d_ws, size_t ws_size,
                              hipStream_t stream) {
  (void)in_sizes; (void)n_in; (void)out_size; (void)d_ws; (void)ws_size;
  const float* Q = (const float*)d_in[0];
  const float* K = (const float*)d_in[1];
  const float* V = (const float*)d_in[2];
  float* O = (float*)d_out;
  // grid.x = batch so all q-tile blocks of a batch share an XCD (L2 reuse)
  dim3 grid(64, 2048 / 256, 1);
  dim3 block(512, 1, 1);
  hipLaunchKernelGGL(DotProductAttention_44573170598739_kernel,
                     grid, block, 0, stream, Q, K, V, O);
}